// Round 16
// baseline (454.141 us; speedup 1.0000x reference)
//
#include <hip/hip_runtime.h>

#define DI __device__ __forceinline__

typedef _Float16 h2v  __attribute__((ext_vector_type(2)));
typedef _Float16 half8 __attribute__((ext_vector_type(8)));
typedef float    f32x4 __attribute__((ext_vector_type(4)));

DI float frcp(float v)  { return __builtin_amdgcn_rcpf(v); }
DI float fexp2(float v) { return __builtin_amdgcn_exp2f(v); }
DI float fsig(float v)  { return frcp(1.0f + __expf(-v)); }
DI float ftanh(float v) { return 1.0f - 2.0f * frcp(__expf(2.0f * v) + 1.0f); }
DI float dot4(float4 a, float4 b) { return a.x*b.x + a.y*b.y + a.z*b.z + a.w*b.w; }

DI h2v u2h(unsigned u) { return __builtin_bit_cast(h2v, u); }
DI unsigned pkrtz(float a, float b) {
    return __builtin_bit_cast(unsigned, __builtin_amdgcn_cvt_pkrtz(a, b));
}
DI half8 u2h8(uint4 v) { return __builtin_bit_cast(half8, v); }

#define TWO_LOG2E 2.8853900817779268f

// ===================== LSTM scan via MFMA, 16 batches per block =====================
// 512 threads = 8 waves. Per step: gates[512][16b] = W[512x160] @ Z[160][16b] as
// 32 m-tiles x 5 k-tiles of mfma_f32_16x16x32_f16. Wave w owns m-tiles
// {w, w+8, w+16, w+24} = ALL 4 gates of units [16w,16w+16) -> state update is
// wave-local (D: col=batch=lane&15, row=(lane>>4)*4+e; m89-verified mapping).
// A-frags: h-part (16 frags, 64 uints) pinned in VGPRs; x-part (4 frags) in LDS.
// Z[16b][160k] packed f16 in LDS, row stride 84 uints. Biases = MFMA C-init.
template <int MODE>
DI void lstm_mfma(const float* __restrict__ xin,   // + bbase*4096   [16b][128t][32]
                  const float* __restrict__ Wih,   // [512][32]
                  const float* __restrict__ Whh,   // [512][128]
                  const float* __restrict__ bih,
                  const float* __restrict__ bhh,
                  float* __restrict__ rec,          // MODE0: + bbase*32768
                  float* __restrict__ outp,         // MODE1: + bbase*32768 + col
                  unsigned* lds)
{
    const int tid = threadIdx.x;
    const int l  = tid & 63;
    const int w  = tid >> 6;     // wave 0..7
    const int lr = l & 15;       // A-row within tile / D-col (batch)
    const int lg = l >> 4;       // k-group 0..3

    unsigned* Z  = lds;          // [16][84] uints: k 0..15 = x (32 halfs), 16..79 = h (128 halfs)
    unsigned* WX = lds + 1344;   // x-part A-frags: [8w][4j][64l][4]

    // ---- A-fragments: W row g = 128j + 16w + lr, k-elems lg*8..+8 of each k-tile ----
    uint4 whA[4][4];
    #pragma unroll
    for (int j = 0; j < 4; ++j) {
        const int g = 128*j + 16*w + lr;
        #pragma unroll
        for (int kt = 1; kt <= 4; ++kt) {
            const float4* p = (const float4*)(Whh + g*128 + (kt-1)*32 + lg*8);
            const float4 a = p[0], b2 = p[1];
            whA[j][kt-1] = make_uint4(pkrtz(a.x,a.y), pkrtz(a.z,a.w),
                                      pkrtz(b2.x,b2.y), pkrtz(b2.z,b2.w));
        }
        const float4* q = (const float4*)(Wih + g*32 + lg*8);
        const float4 a = q[0], b2 = q[1];
        *(uint4*)(WX + ((w*4 + j)*64 + l)*4) =
            make_uint4(pkrtz(a.x,a.y), pkrtz(a.z,a.w), pkrtz(b2.x,b2.y), pkrtz(b2.z,b2.w));
    }
    #pragma unroll
    for (int j = 0; j < 4; ++j)
        #pragma unroll
        for (int kt = 0; kt < 4; ++kt)
            asm volatile("" : "+v"(whA[j][kt].x), "+v"(whA[j][kt].y),
                               "+v"(whA[j][kt].z), "+v"(whA[j][kt].w));

    // biases packed f16, D-row mapping: gate g = 128j + 16w + lg*4 + e
    unsigned bp[8];
    #pragma unroll
    for (int j = 0; j < 4; ++j) {
        const int g0 = 128*j + 16*w + lg*4;
        bp[2*j]   = pkrtz(bih[g0]   + bhh[g0],   bih[g0+1] + bhh[g0+1]);
        bp[2*j+1] = pkrtz(bih[g0+2] + bhh[g0+2], bih[g0+3] + bhh[g0+3]);
    }
    #pragma unroll
    for (int j = 0; j < 8; ++j) asm volatile("" : "+v"(bp[j]));

    float cst[4] = {0.f,0.f,0.f,0.f}, hst[4] = {0.f,0.f,0.f,0.f};

    // init Z: x(0) packed + h zeros
    if (tid < 256) {
        const int b = tid >> 4, i = tid & 15;
        const float2 v = *(const float2*)(xin + b*4096 + 2*i);
        Z[b*84 + i] = pkrtz(v.x, v.y);
    }
    for (int i = tid; i < 1024; i += 512)
        Z[(i >> 6)*84 + 16 + (i & 63)] = 0u;
    __syncthreads();

    const int zrd = lr*84 + lg*4;              // B-frag: col=batch=lr, k=32kt+8lg+e
    const int zwr = lr*84 + 16 + 8*w + lg*2;   // h publish (2 uints = 4 halfs)

    for (int t = 0; t < 128; ++t) {
        float2 xf = make_float2(0.f, 0.f);
        if (tid < 256 && t < 127)
            xf = *(const float2*)(xin + (tid>>4)*4096 + (t+1)*32 + 2*(tid&15));

        f32x4 acc[4];
        #pragma unroll
        for (int j = 0; j < 4; ++j) {
            const h2v p0 = u2h(bp[2*j]), p1 = u2h(bp[2*j+1]);
            acc[j] = (f32x4){(float)p0.x, (float)p0.y, (float)p1.x, (float)p1.y};
        }
        {   // k-tile 0 (x), A from LDS
            const uint4 bf = *(const uint4*)(Z + zrd);
            const half8 B = u2h8(bf);
            #pragma unroll
            for (int j = 0; j < 4; ++j) {
                const uint4 af = *(const uint4*)(WX + ((w*4 + j)*64 + l)*4);
                acc[j] = __builtin_amdgcn_mfma_f32_16x16x32_f16(u2h8(af), B, acc[j], 0, 0, 0);
            }
        }
        #pragma unroll
        for (int kt = 1; kt <= 4; ++kt) {
            const uint4 bf = *(const uint4*)(Z + zrd + kt*16);
            const half8 B = u2h8(bf);
            #pragma unroll
            for (int j = 0; j < 4; ++j)
                acc[j] = __builtin_amdgcn_mfma_f32_16x16x32_f16(u2h8(whA[j][kt-1]), B, acc[j], 0, 0, 0);
        }

        const int u0 = 16*w + lg*4;            // unit base (D-row mapping)
        if (MODE == 0) {                       // pre-step state
            *(float4*)(rec + lr*32768 + t*256 + u0)       = make_float4(hst[0],hst[1],hst[2],hst[3]);
            *(float4*)(rec + lr*32768 + t*256 + 128 + u0) = make_float4(cst[0],cst[1],cst[2],cst[3]);
        }
        #pragma unroll
        for (int e = 0; e < 4; ++e) {
            const float iv = fsig(acc[0][e]);
            const float fv = fsig(acc[1][e]);
            const float gv = ftanh(acc[2][e]);
            const float ov = fsig(acc[3][e]);
            cst[e] = fv*cst[e] + iv*gv;
            hst[e] = ov*ftanh(cst[e]);
        }
        if (MODE == 1)
            *(float4*)(outp + lr*32768 + t*256 + u0) = make_float4(hst[0],hst[1],hst[2],hst[3]);

        __syncthreads();                       // all Z reads done
        *(uint2*)(Z + zwr) = make_uint2(pkrtz(hst[0],hst[1]), pkrtz(hst[2],hst[3]));
        if (tid < 256 && t < 127)
            Z[(tid>>4)*84 + (tid&15)] = pkrtz(xf.x, xf.y);
        __syncthreads();                       // Z(t+1) ready
    }
}

// ===================== self-attention, half-b blocks (64 t per block) =====================
DI void selfatt_half(const float* __restrict__ x, const float* __restrict__ Wg,
                     const float* __restrict__ bg, const float* __restrict__ Wa,
                     const float* __restrict__ ba, float* __restrict__ sa,
                     int b, int hf, float* s)
{
    float* xl  = s;                // 64*33 = 2112
    float* Wgl = s + 2112;         // 4224
    float* WaT = s + 6336;         // 4224
    float* bgl = s + 10560;        // 128
    float* bal = s + 10688;        // 32
    float* gl  = s + 10720;        // 512
    float* pp  = s + 11232;        // 512

    const int tid = threadIdx.x;
    for (int i = tid; i < 2048; i += 512) {
        const int r = i >> 5, n = i & 31;
        xl[r * 33 + n] = x[b * 4096 + (hf * 64 + r) * 32 + n];
    }
    for (int i = tid; i < 4096; i += 512) {
        Wgl[(i >> 5) * 33 + (i & 31)] = Wg[i];
        WaT[(i & 127) * 33 + (i >> 7)] = Wa[i];
    }
    if (tid < 128) bgl[tid] = bg[tid];
    else if (tid < 160) bal[tid - 128] = ba[tid - 128];
    __syncthreads();

    const int tl = tid >> 7;          // 0..3
    for (int it = 0; it < 16; ++it) {
        {   const int m = tid & 127;
            const int tloc = it * 4 + tl;
            float acc = bgl[m];
            #pragma unroll
            for (int n = 0; n < 32; ++n) acc += xl[tloc * 33 + n] * Wgl[m * 33 + n];
            gl[tl * 128 + m] = ftanh(acc);
        }
        __syncthreads();
        {   const int n = tid & 31, c = (tid >> 5) & 3;
            float acc = 0.f;
            #pragma unroll
            for (int j = 0; j < 32; ++j) {
                const int m = c * 32 + j;
                acc += gl[tl * 128 + m] * WaT[m * 33 + n];
            }
            pp[(tl * 4 + c) * 32 + n] = acc;
        }
        __syncthreads();
        if (tid < 128) {
            const int tl2 = tid >> 5, n = tid & 31;
            const int tloc = it * 4 + tl2;
            const float sv = pp[(tl2*4+0)*32+n] + pp[(tl2*4+1)*32+n]
                           + pp[(tl2*4+2)*32+n] + pp[(tl2*4+3)*32+n] + bal[n];
            sa[b * 4096 + (hf * 64 + tloc) * 32 + n] = fsig(sv) * xl[tloc * 33 + n];
        }
        __syncthreads();
    }
}

// k1: blocks 0..7 -> LSTM0-MFMA (16 b each, record rec); 8..263 -> self-attention halves
__global__ __launch_bounds__(512)
void k1_lstm0_sa(const float* __restrict__ x,
                 const float* __restrict__ Wih0, const float* __restrict__ Whh0,
                 const float* __restrict__ bih0, const float* __restrict__ bhh0,
                 const float* __restrict__ Wg, const float* __restrict__ bg,
                 const float* __restrict__ Wa, const float* __restrict__ ba,
                 float* __restrict__ rec, float* __restrict__ sa)
{
    __shared__ float smem[11744];
    const int blk = blockIdx.x;
    if (blk < 8) {
        const long bbase = (long)blk * 16;
        lstm_mfma<0>(x + bbase * 4096, Wih0, Whh0, bih0, bhh0,
                     rec + bbase * 32768, nullptr, (unsigned*)smem);
    } else {
        const int idx = blk - 8;
        selfatt_half(x, Wg, bg, Wa, ba, sa, idx >> 1, idx & 1, smem);
    }
}

// k3: blocks 0..7 -> LSTM1 (ia -> out cols 0..127); 8..15 -> LSTM2 (sa -> cols 128..255)
__global__ __launch_bounds__(512)
void k3_lstm12(const float* __restrict__ ia, const float* __restrict__ sa,
               const float* __restrict__ Wih1, const float* __restrict__ Whh1,
               const float* __restrict__ bih1, const float* __restrict__ bhh1,
               const float* __restrict__ Wih2, const float* __restrict__ Whh2,
               const float* __restrict__ bih2, const float* __restrict__ bhh2,
               float* __restrict__ out)
{
    __shared__ float smem[9536];
    const int blk = blockIdx.x;
    if (blk < 8) {
        const long bbase = (long)blk * 16;
        lstm_mfma<1>(ia + bbase * 4096, Wih1, Whh1, bih1, bhh1,
                     nullptr, out + bbase * 32768, (unsigned*)smem);
    } else {
        const long bbase = (long)(blk - 8) * 16;
        lstm_mfma<1>(sa + bbase * 4096, Wih2, Whh2, bih2, bhh2,
                     nullptr, out + bbase * 32768 + 128, (unsigned*)smem);
    }
}

// ===================== kP (separate-output): w2[b][t][m] = 2*log2e*(We @ [h;c]) =====================
__global__ __launch_bounds__(512, 1)
void kP_w2_sep(const float* __restrict__ We, const float* __restrict__ rec,
               float* __restrict__ w2)
{
    __shared__ float smem[12544];          // hsB 32*260 | wbuf 32*132
    float* hsB  = smem;
    float* wbuf = smem + 8320;
    const int tid = threadIdx.x;
    const int b  = blockIdx.x >> 1;
    const int hh = blockIdx.x & 1;
    const int m = tid >> 2, q = tid & 3;

    float4 wer[16];
    {
        const float4* p = (const float4*)(We + m * 256 + q * 64);
        #pragma unroll
        for (int i = 0; i < 16; ++i) wer[i] = p[i];
    }
    #pragma unroll
    for (int i = 0; i < 16; i += 4) {
        asm volatile("" : "+v"(wer[i].x), "+v"(wer[i].y), "+v"(wer[i].z), "+v"(wer[i].w),
                          "+v"(wer[i+1].x), "+v"(wer[i+1].y), "+v"(wer[i+1].z), "+v"(wer[i+1].w),
                          "+v"(wer[i+2].x), "+v"(wer[i+2].y), "+v"(wer[i+2].z), "+v"(wer[i+2].w),
                          "+v"(wer[i+3].x), "+v"(wer[i+3].y), "+v"(wer[i+3].z), "+v"(wer[i+3].w));
    }

    for (int t2 = 0; t2 < 2; ++t2) {
        const int tb = hh * 2 + t2;
        __syncthreads();
        for (int i = tid; i < 8192; i += 512)
            hsB[(i >> 8) * 260 + (i & 255)] = rec[(long)b * 32768 + (tb * 32 + (i >> 8)) * 256 + (i & 255)];
        __syncthreads();
        for (int tl = 0; tl < 32; ++tl) {
            const float4* h4 = (const float4*)(hsB + tl * 260 + q * 64);
            float acc = 0.f;
            #pragma unroll
            for (int i = 0; i < 16; ++i) acc += dot4(wer[i], h4[i]);
            acc += __shfl_xor(acc, 1);
            acc += __shfl_xor(acc, 2);
            if (q == 0) wbuf[tl * 132 + m] = acc;
        }
        __syncthreads();
        for (int i = tid; i < 4096; i += 512)
            w2[(long)b * 16384 + tb * 4096 + i] = TWO_LOG2E * wbuf[(i >> 7) * 132 + (i & 127)];
    }
}

// kP fallback: in-place into rec, 128 blocks, tb-sequential flush safety.
__global__ __launch_bounds__(512, 1)
void kP_w2_inplace(const float* __restrict__ We, float* __restrict__ rec)
{
    __shared__ float smem[12544];
    float* hsB  = smem;
    float* wbuf = smem + 8320;
    const int tid = threadIdx.x;
    const int b = blockIdx.x;
    const int m = tid >> 2, q = tid & 3;

    float4 wer[16];
    {
        const float4* p = (const float4*)(We + m * 256 + q * 64);
        #pragma unroll
        for (int i = 0; i < 16; ++i) wer[i] = p[i];
    }
    #pragma unroll
    for (int i = 0; i < 16; i += 4) {
        asm volatile("" : "+v"(wer[i].x), "+v"(wer[i].y), "+v"(wer[i].z), "+v"(wer[i].w),
                          "+v"(wer[i+1].x), "+v"(wer[i+1].y), "+v"(wer[i+1].z), "+v"(wer[i+1].w),
                          "+v"(wer[i+2].x), "+v"(wer[i+2].y), "+v"(wer[i+2].z), "+v"(wer[i+2].w),
                          "+v"(wer[i+3].x), "+v"(wer[i+3].y), "+v"(wer[i+3].z), "+v"(wer[i+3].w));
    }

    for (int tb = 0; tb < 4; ++tb) {
        __syncthreads();
        for (int i = tid; i < 8192; i += 512)
            hsB[(i >> 8) * 260 + (i & 255)] = rec[(long)b * 32768 + (tb * 32 + (i >> 8)) * 256 + (i & 255)];
        __syncthreads();
        for (int tl = 0; tl < 32; ++tl) {
            const float4* h4 = (const float4*)(hsB + tl * 260 + q * 64);
            float acc = 0.f;
            #pragma unroll
            for (int i = 0; i < 16; ++i) acc += dot4(wer[i], h4[i]);
            acc += __shfl_xor(acc, 1);
            acc += __shfl_xor(acc, 2);
            if (q == 0) wbuf[tl * 132 + m] = acc;
        }
        __syncthreads();
        for (int i = tid; i < 4096; i += 512)
            rec[(long)b * 32768 + tb * 4096 + i] = TWO_LOG2E * wbuf[(i >> 7) * 132 + (i & 127)];
    }
}

// ===================== kB: input attention (exp2 domain) =====================
__global__ __launch_bounds__(512, 2)
void kB_attn(const float* __restrict__ x,    // [128][128][32]
             const float* __restrict__ Ue,   // [128][32]
             const float* __restrict__ Ve,   // [128]
             const float* __restrict__ w2g,  // [b][t][128] pre-scaled, stride bstr per b
             long bstr,
             float* __restrict__ ia)         // [128][128][32]
{
    __shared__ float xl[4608];     // [tau][36]
    __shared__ float wl[4224];     // [32 t][132]
    __shared__ float uxc[4224];    // [32 m][132 tau]
    __shared__ float UeAv[4608];   // Uel [128][36] during e-phase; av [32 t][128] after
    __shared__ float vel[128];     // 2*Ve
    __shared__ float sinv[32];
    __shared__ float iap[576];     // [16][36]

    const int tid = threadIdx.x;
    const int b  = blockIdx.x >> 2;
    const int tc = blockIdx.x & 3;

    for (int i = tid; i < 4096; i += 512) {
        xl[(i >> 5) * 36 + (i & 31)]   = x[b * 4096 + i];
        UeAv[(i >> 5) * 36 + (i & 31)] = Ue[i];
        wl[(i >> 7) * 132 + (i & 127)] = w2g[(long)b * bstr + (tc * 32 + (i >> 7)) * 128 + (i & 127)];
    }
    if (tid < 128) vel[tid] = 2.0f * Ve[tid];
    __syncthreads();

    const int ts = tid & 127, mg = tid >> 7;
    float4 xr[8];
    {
        const float4* xp = (const float4*)(xl + ts * 36);
        #pragma unroll
        for (int i = 0; i < 8; ++i) xr[i] = xp[i];
    }
    float VeTot = 0.f;
    for (int i = 0; i < 128; ++i) VeTot += vel[i];
    VeTot *= 0.5f;

    const int tp = tid >> 5, tg = tid & 31;
    const int t0 = 2 * tp, t1 = t0 + 1;
    float s0[4] = {0.f, 0.f, 0.f, 0.f};
    float s1[4] = {0.f, 0.f, 0.f, 0.f};

    for (int mc = 0; mc < 4; ++mc) {
        #pragma unroll
        for (int j = 0; j < 8; ++j) {
            const int ml = mg * 8 + j;
            const float4* u4 = (const float4*)(UeAv + (mc * 32 + ml) * 36);
            float acc = 0.f;
            #pragma unroll
            for (int i = 0; i < 8; ++i) acc += dot4(xr[i], u4[i]);
            uxc[ml * 132 + ts] = TWO_LOG2E * acc;
        }
        __syncthreads();
        #pragma unroll 8
        for (int ml = 0; ml < 32; ++ml) {
            const int m = mc * 32 + ml;
            const float vm = vel[m];
            const float w0 = wl[t0 * 132 + m];
            const float w1 = wl[t1 * 132 + m];
            const float4 u4 = *(const float4*)(uxc + ml * 132 + 4 * tg);
            s0[0] += vm * frcp(fexp2(u4.x + w0) + 1.0f);
            s0[1] += vm * frcp(fexp2(u4.y + w0) + 1.0f);
            s0[2] += vm * frcp(fexp2(u4.z + w0) + 1.0f);
            s0[3] += vm * frcp(fexp2(u4.w + w0) + 1.0f);
            s1[0] += vm * frcp(fexp2(u4.x + w1) + 1.0f);
            s1[1] += vm * frcp(fexp2(u4.y + w1) + 1.0f);
            s1[2] += vm * frcp(fexp2(u4.z + w1) + 1.0f);
            s1[3] += vm * frcp(fexp2(u4.w + w1) + 1.0f);
        }
        __syncthreads();
    }

    float e0[4], e1[4];
    #pragma unroll
    for (int j = 0; j < 4; ++j) { e0[j] = VeTot - s0[j]; e1[j] = VeTot - s1[j]; }
    float M0 = fmaxf(fmaxf(e0[0], e0[1]), fmaxf(e0[2], e0[3]));
    float M1 = fmaxf(fmaxf(e1[0], e1[1]), fmaxf(e1[2], e1[3]));
    #pragma unroll
    for (int o = 1; o < 32; o <<= 1) {
        M0 = fmaxf(M0, __shfl_xor(M0, o));
        M1 = fmaxf(M1, __shfl_xor(M1, o));
    }
    float a00 = __expf(e0[0] - M0), a01 = __expf(e0[1] - M0);
    float a02 = __expf(e0[2] - M0), a03 = __expf(e0[3] - M0);
    float a10 = __expf(e1[0] - M1), a11 = __expf(e1[1] - M1);
    float a12 = __expf(e1[2] - M1), a13 = __expf(e1[3] - M1);
    float S0 = a00 + a01 + a02 + a03;
    float S1 = a10 + a11 + a12 + a13;
    #pragma unroll
    for (int o = 1; o < 32; o <<= 1) {
        S0 += __shfl_xor(S0, o);
        S1 += __shfl_xor(S1, o);
    }
    float* av = UeAv;
    *(float4*)(av + t0 * 128 + 4 * tg) = make_float4(a00, a01, a02, a03);
    *(float4*)(av + t1 * 128 + 4 * tg) = make_float4(a10, a11, a12, a13);
    if (tg == 0) { sinv[t0] = frcp(S0); sinv[t1] = frcp(S1); }
    __syncthreads();

    const int gph = tid >> 5, n = tid & 31;
    for (int tl = 0; tl < 32; ++tl) {
        float acc = 0.f;
        #pragma unroll
        for (int j = 0; j < 8; ++j)
            acc += av[tl * 128 + gph * 8 + j] * xl[(gph * 8 + j) * 36 + n];
        iap[gph * 36 + n] = acc;
        __syncthreads();
        if (tid < 32) {
            float s = 0.f;
            #pragma unroll
            for (int g = 0; g < 16; ++g) s += iap[g * 36 + tid];
            ia[((long)(b * 128 + tc * 32 + tl)) * 32 + tid] = s * sinv[tl];
        }
        __syncthreads();
    }
}

extern "C" void kernel_launch(void* const* d_in, const int* in_sizes, int n_in,
                              void* d_out, int out_size, void* d_ws, size_t ws_size,
                              hipStream_t stream)
{
    const float* x    = (const float*)d_in[0];
    const float* Wih0 = (const float*)d_in[1];
    const float* Whh0 = (const float*)d_in[2];
    const float* bih0 = (const float*)d_in[3];
    const float* bhh0 = (const float*)d_in[4];
    const float* We   = (const float*)d_in[5];
    const float* Ue   = (const float*)d_in[6];
    const float* Ve   = (const float*)d_in[7];
    const float* Wg   = (const float*)d_in[8];
    const float* bg   = (const float*)d_in[9];
    const float* Wa   = (const float*)d_in[10];
    const float* ba   = (const float*)d_in[11];
    const float* Wih1 = (const float*)d_in[12];
    const float* Whh1 = (const float*)d_in[13];
    const float* bih1 = (const float*)d_in[14];
    const float* bhh1 = (const float*)d_in[15];
    const float* Wih2 = (const float*)d_in[16];
    const float* Whh2 = (const float*)d_in[17];
    const float* bih2 = (const float*)d_in[18];
    const float* bhh2 = (const float*)d_in[19];

    float* out = (float*)d_out;
    float* ws  = (float*)d_ws;
    // workspace (floats): sa 524288 | rec 4194304 | ia 524288 | [w2 2097152 if room]
    float* sa  = ws;
    float* rec = ws + 524288;
    float* iaw = ws + 4718592;
    float* w2  = ws + 5242880;
    const bool sep = ws_size >= (size_t)7340032 * 4;   // 28 MiB

    k1_lstm0_sa<<<264, 512, 0, stream>>>(x, Wih0, Whh0, bih0, bhh0,
                                         Wg, bg, Wa, ba, rec, sa);
    if (sep) {
        kP_w2_sep<<<256, 512, 0, stream>>>(We, rec, w2);
        kB_attn<<<512, 512, 0, stream>>>(x, Ue, Ve, w2, 16384L, iaw);
    } else {
        kP_w2_inplace<<<128, 512, 0, stream>>>(We, rec);
        kB_attn<<<512, 512, 0, stream>>>(x, Ue, Ve, rec, 32768L, iaw);
    }
    k3_lstm12<<<16, 512, 0, stream>>>(iaw, sa, Wih1, Whh1, bih1, bhh1,
                                      Wih2, Whh2, bih2, bhh2, out);
}